// Round 1
// baseline (9879.016 us; speedup 1.0000x reference)
//
#include <hip/hip_runtime.h>
#include <math.h>

#define B 256
#define N 256
#define EPS 1e-5

// ---------------------------------------------------------------------------
// Kernel 1: column sums of (exp(x)+EPS) with diagonal excluded.  cs[b][j].
// Coalesced: thread j reads x[b][i][j] for i=0..N-1.
// ---------------------------------------------------------------------------
__global__ void colsum_k(const float* __restrict__ x, double* __restrict__ cs) {
    int b = blockIdx.x;
    int j = threadIdx.x;
    const float* xb = x + (size_t)b * N * N;
    double s = 0.0;
    for (int i = 0; i < N; ++i) {
        if (i != j) s += exp((double)xb[i * N + j]) + EPS;
    }
    cs[b * N + j] = s;
}

// ---------------------------------------------------------------------------
// Kernel 2: build the modified Laplacian (fp64) into A.
//   row 0   : A[0][j] = exp(x[j][j])          (root scores)
//   i==j>0  : A[i][i] = colsum_i
//   else    : A[i][j] = -(exp(x[i][j]) + EPS)
// ---------------------------------------------------------------------------
__global__ void build_k(const float* __restrict__ x, const double* __restrict__ cs,
                        double* __restrict__ Aall) {
    int i = blockIdx.x;
    int b = blockIdx.y;
    int j = threadIdx.x;
    const float* xb = x + (size_t)b * N * N;
    double* A = Aall + (size_t)b * N * N;
    double v;
    if (i == 0) {
        v = exp((double)xb[j * N + j]);
    } else if (j == i) {
        v = cs[b * N + j];
    } else {
        v = -(exp((double)xb[i * N + j]) + EPS);
    }
    A[i * N + j] = v;
}

// ---------------------------------------------------------------------------
// Kernel 3: in-place Gauss-Jordan inversion with partial (row) pivoting.
// One 1024-thread block per batch. NR gaussj scheme: physical row swaps during
// elimination, column unswap in reverse order afterwards.
// Thread mapping: j = tid & 255 (column), ty = tid >> 8 (row phase 0..3).
// ---------------------------------------------------------------------------
__global__ __launch_bounds__(1024) void gj_inv(double* __restrict__ Aall) {
    int b = blockIdx.x;
    double* A = Aall + (size_t)b * N * N;
    int tid = threadIdx.x;
    int j = tid & (N - 1);
    int ty = tid >> 8;

    __shared__ double srow[N];   // pivot row * pivinv
    __shared__ double scol[N];   // pivot column (pre-update values)
    __shared__ double spiv;      // 1/pivot
    __shared__ int    spidx;     // pivot row index
    __shared__ int    indx[N];   // pivot history for unscramble
    __shared__ double wabs[4];
    __shared__ double wval[4];
    __shared__ int    widx[4];

    for (int k = 0; k < N; ++k) {
        // --- partial pivot search on column k, rows k..N-1 (ty==0 waves) ---
        if (ty == 0) {
            double v  = A[j * N + k];
            double av = (j >= k) ? fabs(v) : -1.0;
            int idx = j;
            for (int off = 32; off > 0; off >>= 1) {
                double oav = __shfl_down(av, off);
                double ov  = __shfl_down(v, off);
                int    oi  = __shfl_down(idx, off);
                if (oav > av) { av = oav; v = ov; idx = oi; }
            }
            if ((tid & 63) == 0) {
                int w = tid >> 6;
                wabs[w] = av; wval[w] = v; widx[w] = idx;
            }
        }
        __syncthreads();
        if (tid == 0) {
            double av = wabs[0]; double v = wval[0]; int idx = widx[0];
            for (int w = 1; w < 4; ++w)
                if (wabs[w] > av) { av = wabs[w]; v = wval[w]; idx = widx[w]; }
            spidx = idx;
            spiv  = 1.0 / v;
            indx[k] = idx;
        }
        __syncthreads();
        int p = spidx;
        double pivinv = spiv;

        // --- physical row swap k <-> p ---
        if (p != k && ty == 0) {
            double t1 = A[k * N + j];
            double t2 = A[p * N + j];
            A[k * N + j] = t2;
            A[p * N + j] = t1;
        }
        __syncthreads();

        // --- stage scaled pivot row and pivot column in LDS ---
        if (ty == 0) {
            double rv = A[k * N + j];
            srow[j] = (j == k) ? pivinv : rv * pivinv;
        } else if (ty == 1) {
            scol[j] = (j == k) ? 0.0 : A[j * N + k];
        }
        __syncthreads();

        // write scaled pivot row back (row k owned exclusively here)
        if (ty == 0) A[k * N + j] = srow[j];

        // --- rank-1 update of all rows i != k ---
        for (int ib = 0; ib < N; ib += 4) {
            int i = ib + ty;
            if (i == k) continue;
            double c = scol[i];
            double a = A[i * N + j];
            double base = (j == k) ? 0.0 : a;     // column k gets -c*pivinv
            A[i * N + j] = fma(-c, srow[j], base);
        }
        __syncthreads();
    }

    // --- unscramble: swap columns in reverse pivot order.
    // Thread j (ty==0) owns row j for every swap -> no barriers needed.
    if (ty == 0) {
        for (int k = N - 1; k >= 0; --k) {
            int p = indx[k];
            if (p != k) {
                double t1 = A[j * N + k];
                double t2 = A[j * N + p];
                A[j * N + k] = t2;
                A[j * N + p] = t1;
            }
        }
    }
}

// ---------------------------------------------------------------------------
// Kernel 4: epilogue.
//  out[b,i,j] = (j!=0)*e_ij*inv[j,j] - (i!=0)*e_ij*inv[j,i] + (i==j)*e_ii*inv[i,0]
// ---------------------------------------------------------------------------
__global__ void finalize(const float* __restrict__ x, const double* __restrict__ Inv,
                         float* __restrict__ out) {
    int b = blockIdx.x;
    int j = threadIdx.x;
    const double* Iv = Inv + (size_t)b * N * N;
    const float*  xb = x   + (size_t)b * N * N;
    float*        ob = out + (size_t)b * N * N;

    __shared__ double sdiag[N];  // inv[j][j]
    __shared__ double sroot[N];  // inv[i][0]
    sdiag[j] = Iv[j * N + j];
    sroot[j] = Iv[j * N + 0];
    __syncthreads();

    for (int i = 0; i < N; ++i) {
        double e  = exp((double)xb[i * N + j]);
        double t1 = (j == 0) ? 0.0 : e * sdiag[j];
        double t2 = (i == 0) ? 0.0 : e * Iv[j * N + i];   // inv^T[i][j]
        double o  = t1 - t2;
        if (i == j) o += e * sroot[i];
        ob[i * N + j] = (float)o;
    }
}

extern "C" void kernel_launch(void* const* d_in, const int* in_sizes, int n_in,
                              void* d_out, int out_size, void* d_ws, size_t ws_size,
                              hipStream_t stream) {
    const float* x = (const float*)d_in[0];
    float* out = (float*)d_out;

    size_t bytesA  = (size_t)B * N * N * sizeof(double);   // 128 MiB
    size_t bytesCS = (size_t)B * N * sizeof(double);       // 512 KiB
    if (ws_size < bytesA + bytesCS) return;                // ws too small: fail visibly

    double* A  = (double*)d_ws;
    double* cs = (double*)((char*)d_ws + bytesA);

    colsum_k<<<B, N, 0, stream>>>(x, cs);
    build_k<<<dim3(N, B), N, 0, stream>>>(x, cs, A);
    gj_inv<<<B, 1024, 0, stream>>>(A);
    finalize<<<B, N, 0, stream>>>(x, A, out);
}

// Round 2
// 2704.625 us; speedup vs baseline: 3.6526x; 3.6526x over previous
//
#include <hip/hip_runtime.h>
#include <math.h>

#define B 256
#define N 256
#define EPS 1e-5
#define BS 32
#define NB (N / BS)

// ---------------------------------------------------------------------------
// Kernel 1: column sums of (exp(x)+EPS) with diagonal excluded.  cs[b][j].
// ---------------------------------------------------------------------------
__global__ void colsum_k(const float* __restrict__ x, double* __restrict__ cs) {
    int b = blockIdx.x;
    int j = threadIdx.x;
    const float* xb = x + (size_t)b * N * N;
    double s = 0.0;
    for (int i = 0; i < N; ++i) {
        if (i != j) s += exp((double)xb[i * N + j]) + EPS;
    }
    cs[b * N + j] = s;
}

// ---------------------------------------------------------------------------
// Kernel 2: build the modified Laplacian (fp64) into A.
// ---------------------------------------------------------------------------
__global__ void build_k(const float* __restrict__ x, const double* __restrict__ cs,
                        double* __restrict__ Aall) {
    int i = blockIdx.x;
    int b = blockIdx.y;
    int j = threadIdx.x;
    const float* xb = x + (size_t)b * N * N;
    double* A = Aall + (size_t)b * N * N;
    double v;
    if (i == 0) {
        v = exp((double)xb[j * N + j]);
    } else if (j == i) {
        v = cs[b * N + j];
    } else {
        v = -(exp((double)xb[i * N + j]) + EPS);
    }
    A[i * N + j] = v;
}

// ---------------------------------------------------------------------------
// Kernel 3: BLOCKED in-place Gauss-Jordan inversion, block size 32.
// One 1024-thread block per batch. Pivot block inverted in LDS with partial
// pivoting (local); row/col panels staged in LDS; rank-32 updates register-
// tiled (2 cols x 4 rows per thread, ds_read_b128 on the row panel).
//
// Block-2x2 recursion check ([[A,B],[C,D]], P=A^-1, S=D-CPB, P2=S^-1):
//   step0: [[P, PB], [-CP, S]]  step1: [[P+PB P2 CP, -PB P2], [-P2 CP, P2]]
// == exact 2x2 block inverse.
// ---------------------------------------------------------------------------
__global__ __launch_bounds__(1024) void gj_blocked(double* __restrict__ Aall) {
    __shared__ alignas(16) double Rsh[BS][N];     // row panel  (64 KB)
    __shared__ alignas(16) double Csh[N][BS];     // col panel  (64 KB)
    __shared__ double Psh[BS][BS + 1];            // pivot block (8.25 KB)
    __shared__ double spiv_s;
    __shared__ int    spidx_s;
    __shared__ int    indx[BS];

    double* A = Aall + (size_t)blockIdx.x * N * N;
    const int tid = threadIdx.x;
    const int j0  = (tid & 127) << 1;   // even column, 0..254
    const int rq  = tid >> 7;           // 0..7

    for (int kb = 0; kb < NB; ++kb) {
        const int k0 = kb * BS;
        const bool jactive = ((j0 >> 5) != kb);

        // ---- stage row panel, col panel, pivot block ----
        {
            const int j = tid & 255, r4 = tid >> 8;
#pragma unroll
            for (int s = 0; s < 8; ++s) {
                const int r = r4 + 4 * s;
                Rsh[r][j] = A[(size_t)(k0 + r) * N + j];
            }
            const int kk = tid & 31, iq = tid >> 5;
#pragma unroll
            for (int p = 0; p < 8; ++p) {
                const int i = iq + 32 * p;
                Csh[i][kk] = A[(size_t)i * N + k0 + kk];
            }
            Psh[tid >> 5][tid & 31] = A[(size_t)(k0 + (tid >> 5)) * N + k0 + (tid & 31)];
        }
        __syncthreads();

        // ---- invert pivot block in LDS (GJ, partial pivoting) ----
        {
            const int r = tid >> 5, c = tid & 31;
            for (int k2 = 0; k2 < BS; ++k2) {
                if (tid < 64) {  // one wave does the pivot search
                    int rr = tid & 31;
                    double v  = Psh[rr][k2];
                    double av = (tid < 32 && rr >= k2) ? fabs(v) : -1.0;
                    int idx = rr;
                    for (int off = 16; off > 0; off >>= 1) {
                        double oav = __shfl_down(av, off);
                        double ov  = __shfl_down(v, off);
                        int    oi  = __shfl_down(idx, off);
                        if (oav > av) { av = oav; v = ov; idx = oi; }
                    }
                    if (tid == 0) { spidx_s = idx; spiv_s = 1.0 / v; indx[k2] = idx; }
                }
                __syncthreads();
                const int p = spidx_s;
                const double pivinv = spiv_s;
                // fused virtual-swap + eliminate: all reads are pre-swap
                const int sr = (r == k2) ? p : ((r == p) ? k2 : r);
                const double aval  = Psh[sr][c];          // S[r][c]
                const double prow  = Psh[p][c];           // new pivot row (unscaled)
                const double scolr = Psh[sr][k2];         // S[r][k2]
                __syncthreads();
                double nv;
                if (r == k2) {
                    nv = (c == k2) ? pivinv : prow * pivinv;
                } else {
                    const double srw  = (c == k2) ? pivinv : prow * pivinv;
                    const double base = (c == k2) ? 0.0 : aval;
                    nv = fma(-scolr, srw, base);
                }
                Psh[r][c] = nv;
                __syncthreads();
            }
            // column unscramble (thread r owns row r; independent swaps)
            if (tid < 32) {
                for (int k2 = BS - 1; k2 >= 0; --k2) {
                    const int p = indx[k2];
                    if (p != k2) {
                        double t = Psh[tid][k2];
                        Psh[tid][k2] = Psh[tid][p];
                        Psh[tid][p]  = t;
                    }
                }
            }
            __syncthreads();
        }

        // ---- R' = P * R ; Rsh <- R'; write row block (diag cols <- P) ----
        {
            double acc[4][2];
            if (jactive) {
#pragma unroll
                for (int s = 0; s < 4; ++s) { acc[s][0] = 0.0; acc[s][1] = 0.0; }
                for (int kk = 0; kk < BS; ++kk) {
                    const double2 rv = *(const double2*)&Rsh[kk][j0];
#pragma unroll
                    for (int s = 0; s < 4; ++s) {
                        const double pv = Psh[rq + 8 * s][kk];
                        acc[s][0] = fma(pv, rv.x, acc[s][0]);
                        acc[s][1] = fma(pv, rv.y, acc[s][1]);
                    }
                }
            }
            __syncthreads();
#pragma unroll
            for (int s = 0; s < 4; ++s) {
                const int r = rq + 8 * s;
                double2 st;
                if (jactive) {
                    Rsh[r][j0]     = acc[s][0];
                    Rsh[r][j0 + 1] = acc[s][1];
                    st.x = acc[s][0]; st.y = acc[s][1];
                } else {
                    st.x = Psh[r][j0 - k0];
                    st.y = Psh[r][j0 - k0 + 1];
                }
                *(double2*)&A[(size_t)(k0 + r) * N + j0] = st;
            }
        }
        __syncthreads();   // Rsh now holds R' (GEMM reads it)

        // ---- C' = -C * P  -> global col block (rows outside pivot block) ----
        {
            const int kk = tid & 31, iq = tid >> 5;
            double acc[8];
#pragma unroll
            for (int p = 0; p < 8; ++p) acc[p] = 0.0;
            for (int m = 0; m < BS; ++m) {
                const double pv = Psh[m][kk];
#pragma unroll
                for (int p = 0; p < 8; ++p)
                    acc[p] = fma(Csh[iq + 32 * p][m], pv, acc[p]);
            }
#pragma unroll
            for (int p = 0; p < 8; ++p) {
                if (p != kb) A[(size_t)(iq + 32 * p) * N + k0 + kk] = -acc[p];
            }
        }
        // no barrier needed: GEMM below touches disjoint global columns and
        // only reads Rsh/Csh (unmodified here).

        // ---- trailing/leading update: A[rb][jactive] -= C[rb] * R' ----
        if (jactive) {
            for (int rb = 0; rb < NB; ++rb) {
                if (rb == kb) continue;
                const int rbase = rb * BS;
                double2 acc[4];
#pragma unroll
                for (int s = 0; s < 4; ++s)
                    acc[s] = *(const double2*)&A[(size_t)(rbase + rq + 8 * s) * N + j0];
                for (int kk = 0; kk < BS; ++kk) {
                    const double2 rv = *(const double2*)&Rsh[kk][j0];
#pragma unroll
                    for (int s = 0; s < 4; ++s) {
                        const double c = Csh[rbase + rq + 8 * s][kk];
                        acc[s].x = fma(-c, rv.x, acc[s].x);
                        acc[s].y = fma(-c, rv.y, acc[s].y);
                    }
                }
#pragma unroll
                for (int s = 0; s < 4; ++s)
                    *(double2*)&A[(size_t)(rbase + rq + 8 * s) * N + j0] = acc[s];
            }
        }
        __syncthreads();   // everyone done with Rsh/Csh/Psh before next stage
    }
}

// ---------------------------------------------------------------------------
// Kernel 4: epilogue.
// ---------------------------------------------------------------------------
__global__ void finalize(const float* __restrict__ x, const double* __restrict__ Inv,
                         float* __restrict__ out) {
    int b = blockIdx.x;
    int j = threadIdx.x;
    const double* Iv = Inv + (size_t)b * N * N;
    const float*  xb = x   + (size_t)b * N * N;
    float*        ob = out + (size_t)b * N * N;

    __shared__ double sdiag[N];
    __shared__ double sroot[N];
    sdiag[j] = Iv[j * N + j];
    sroot[j] = Iv[j * N + 0];
    __syncthreads();

    for (int i = 0; i < N; ++i) {
        double e  = exp((double)xb[i * N + j]);
        double t1 = (j == 0) ? 0.0 : e * sdiag[j];
        double t2 = (i == 0) ? 0.0 : e * Iv[j * N + i];
        double o  = t1 - t2;
        if (i == j) o += e * sroot[i];
        ob[i * N + j] = (float)o;
    }
}

extern "C" void kernel_launch(void* const* d_in, const int* in_sizes, int n_in,
                              void* d_out, int out_size, void* d_ws, size_t ws_size,
                              hipStream_t stream) {
    const float* x = (const float*)d_in[0];
    float* out = (float*)d_out;

    size_t bytesA  = (size_t)B * N * N * sizeof(double);   // 128 MiB
    size_t bytesCS = (size_t)B * N * sizeof(double);
    if (ws_size < bytesA + bytesCS) return;

    double* A  = (double*)d_ws;
    double* cs = (double*)((char*)d_ws + bytesA);

    colsum_k<<<B, N, 0, stream>>>(x, cs);
    build_k<<<dim3(N, B), N, 0, stream>>>(x, cs, A);
    gj_blocked<<<B, 1024, 0, stream>>>(A);
    finalize<<<B, N, 0, stream>>>(x, A, out);
}

// Round 3
// 2586.232 us; speedup vs baseline: 3.8198x; 1.0458x over previous
//
#include <hip/hip_runtime.h>
#include <math.h>

#define B 256
#define N 256
#define EPS 1e-5f
#define BS 32
#define NB (N / BS)

// ---------------------------------------------------------------------------
// Kernel 1: column sums of (exp(x)+EPS), diagonal excluded. cs[b][j] (fp64).
// 1024 threads: 4 partial sums per column, LDS reduce.
// ---------------------------------------------------------------------------
__global__ __launch_bounds__(1024) void colsum_k(const float* __restrict__ x,
                                                 double* __restrict__ cs) {
    const int b = blockIdx.x;
    const int tid = threadIdx.x;
    const int j = tid & 255, tq = tid >> 8;
    const float* xb = x + (size_t)b * N * N;
    double s = 0.0;
    for (int i = tq; i < N; i += 4) {
        if (i != j) s += (double)expf(xb[(size_t)i * N + j]) + (double)EPS;
    }
    __shared__ double red[4][256];
    red[tq][j] = s;
    __syncthreads();
    if (tq == 0) cs[b * N + j] = red[0][j] + red[1][j] + red[2][j] + red[3][j];
}

// ---------------------------------------------------------------------------
// Kernel 2: build TRANSPOSED Laplacian M = L^T (fp32), tiled transpose of x.
//   M[i][0]   = exp(x[i][i])            (L row 0 = root scores)
//   M[i][i]   = colsum_i (i>0)
//   M[i][j]   = -(exp(x[j][i]) + EPS)   otherwise
// Inverting M gives Minv = inv^T, which finalize reads coalesced.
// ---------------------------------------------------------------------------
__global__ void build_t(const float* __restrict__ x, const double* __restrict__ cs,
                        float* __restrict__ AT) {
    const int b  = blockIdx.y;
    const int i0 = (blockIdx.x >> 3) * 32;   // output row block
    const int j0 = (blockIdx.x & 7) * 32;    // output col block
    const float* xb = x + (size_t)b * N * N;
    float* M = AT + (size_t)b * N * N;
    __shared__ float xs[32][33];
    const int c  = threadIdx.x & 31;
    const int r8 = threadIdx.x >> 5;
#pragma unroll
    for (int m = 0; m < 4; ++m) {
        const int jj = r8 + 8 * m;
        xs[jj][c] = xb[(size_t)(j0 + jj) * N + i0 + c];   // coalesced read of x
    }
    __syncthreads();
#pragma unroll
    for (int m = 0; m < 4; ++m) {
        const int ir = r8 + 8 * m;
        const int ig = i0 + ir, jg = j0 + c;
        float v;
        if (jg == 0) {
            v = expf(xb[(size_t)ig * N + ig]);
        } else if (ig == jg) {
            v = (float)cs[b * N + ig];
        } else {
            v = -(expf(xs[c][ir]) + EPS);                 // x[jg][ig] transposed
        }
        M[(size_t)ig * N + jg] = v;                       // coalesced write
    }
}

// ---------------------------------------------------------------------------
// Kernel 3: blocked in-place Gauss-Jordan, BS=32. fp32 global storage,
// ALL arithmetic fp64 (LDS panels + register accumulators). Trailing update
// software-pipelined (prefetch next row-block while computing current).
// ---------------------------------------------------------------------------
__global__ __launch_bounds__(1024) void gj_blocked(float* __restrict__ Aall) {
    __shared__ alignas(16) double Rsh[BS][N];     // row panel  (64 KB)
    __shared__ alignas(16) double Csh[N][BS];     // col panel  (64 KB)
    __shared__ double Psh[BS][BS + 1];            // pivot block (8.25 KB)
    __shared__ double spiv_s;
    __shared__ int    spidx_s;
    __shared__ int    indx[BS];

    float* A = Aall + (size_t)blockIdx.x * N * N;
    const int tid = threadIdx.x;
    const int j0  = (tid & 127) << 1;   // even column, 0..254
    const int rq  = tid >> 7;           // 0..7

    for (int kb = 0; kb < NB; ++kb) {
        const int k0 = kb * BS;
        const bool jactive = ((j0 >> 5) != kb);

        // ---- stage row panel, col panel, pivot block (fp32 -> fp64 LDS) ----
        {
            const int j = tid & 255, r4 = tid >> 8;
#pragma unroll
            for (int s = 0; s < 8; ++s)
                Rsh[r4 + 4 * s][j] = (double)A[(size_t)(k0 + r4 + 4 * s) * N + j];
            const int kk = tid & 31, iq = tid >> 5;
#pragma unroll
            for (int p = 0; p < 8; ++p)
                Csh[iq + 32 * p][kk] = (double)A[(size_t)(iq + 32 * p) * N + k0 + kk];
            Psh[tid >> 5][tid & 31] =
                (double)A[(size_t)(k0 + (tid >> 5)) * N + k0 + (tid & 31)];
        }
        __syncthreads();

        // ---- invert pivot block in LDS (fp64 GJ, partial pivoting) ----
        {
            const int r = tid >> 5, c = tid & 31;
            for (int k2 = 0; k2 < BS; ++k2) {
                if (tid < 64) {
                    int rr = tid & 31;
                    double v  = Psh[rr][k2];
                    double av = (tid < 32 && rr >= k2) ? fabs(v) : -1.0;
                    int idx = rr;
                    for (int off = 16; off > 0; off >>= 1) {
                        double oav = __shfl_down(av, off);
                        double ov  = __shfl_down(v, off);
                        int    oi  = __shfl_down(idx, off);
                        if (oav > av) { av = oav; v = ov; idx = oi; }
                    }
                    if (tid == 0) { spidx_s = idx; spiv_s = 1.0 / v; indx[k2] = idx; }
                }
                __syncthreads();
                const int p = spidx_s;
                const double pivinv = spiv_s;
                const int sr = (r == k2) ? p : ((r == p) ? k2 : r);
                const double aval  = Psh[sr][c];
                const double prow  = Psh[p][c];
                const double scolr = Psh[sr][k2];
                __syncthreads();
                double nv;
                if (r == k2) {
                    nv = (c == k2) ? pivinv : prow * pivinv;
                } else {
                    const double srw  = (c == k2) ? pivinv : prow * pivinv;
                    const double base = (c == k2) ? 0.0 : aval;
                    nv = fma(-scolr, srw, base);
                }
                Psh[r][c] = nv;
                __syncthreads();
            }
            if (tid < 32) {
                for (int k2 = BS - 1; k2 >= 0; --k2) {
                    const int p = indx[k2];
                    if (p != k2) {
                        double t = Psh[tid][k2];
                        Psh[tid][k2] = Psh[tid][p];
                        Psh[tid][p]  = t;
                    }
                }
            }
            __syncthreads();
        }

        // ---- R' = P * R ; Rsh <- R'; write row block (pivot cols <- P) ----
        {
            double acc[4][2];
            if (jactive) {
#pragma unroll
                for (int s = 0; s < 4; ++s) { acc[s][0] = 0.0; acc[s][1] = 0.0; }
                for (int kk = 0; kk < BS; ++kk) {
                    const double2 rv = *(const double2*)&Rsh[kk][j0];
#pragma unroll
                    for (int s = 0; s < 4; ++s) {
                        const double pv = Psh[rq + 8 * s][kk];
                        acc[s][0] = fma(pv, rv.x, acc[s][0]);
                        acc[s][1] = fma(pv, rv.y, acc[s][1]);
                    }
                }
            }
            __syncthreads();
#pragma unroll
            for (int s = 0; s < 4; ++s) {
                const int r = rq + 8 * s;
                float2 st;
                if (jactive) {
                    Rsh[r][j0]     = acc[s][0];
                    Rsh[r][j0 + 1] = acc[s][1];
                    st.x = (float)acc[s][0]; st.y = (float)acc[s][1];
                } else {
                    st.x = (float)Psh[r][j0 - k0];
                    st.y = (float)Psh[r][j0 - k0 + 1];
                }
                *(float2*)&A[(size_t)(k0 + r) * N + j0] = st;
            }
        }
        __syncthreads();   // Rsh now holds R'

        // ---- C' = -C * P -> global col block (rows outside pivot block) ----
        {
            const int kk = tid & 31, iq = tid >> 5;
            double acc[8];
#pragma unroll
            for (int p = 0; p < 8; ++p) acc[p] = 0.0;
            for (int m = 0; m < BS; ++m) {
                const double pv = Psh[m][kk];
#pragma unroll
                for (int p = 0; p < 8; ++p)
                    acc[p] = fma(Csh[iq + 32 * p][m], pv, acc[p]);
            }
#pragma unroll
            for (int p = 0; p < 8; ++p)
                if (p != kb) A[(size_t)(iq + 32 * p) * N + k0 + kk] = -(float)acc[p];
        }
        // no barrier: trailing touches disjoint global columns, reads only
        // Rsh/Csh (unmodified here).

        // ---- trailing update, software-pipelined: A[rb] -= C[rb] * R' ----
        if (jactive) {
            float2 nxt[4];
            {
                const int rb0 = 0 + (0 >= kb);
#pragma unroll
                for (int s = 0; s < 4; ++s)
                    nxt[s] = *(const float2*)&A[(size_t)(rb0 * BS + rq + 8 * s) * N + j0];
            }
            for (int t = 0; t < NB - 1; ++t) {
                const int rb    = t + (t >= kb);
                const int rbase = rb * BS;
                float2 cur[4];
#pragma unroll
                for (int s = 0; s < 4; ++s) cur[s] = nxt[s];
                if (t + 1 < NB - 1) {
                    const int rbn = (t + 1) + ((t + 1) >= kb);
#pragma unroll
                    for (int s = 0; s < 4; ++s)
                        nxt[s] = *(const float2*)&A[(size_t)(rbn * BS + rq + 8 * s) * N + j0];
                }
                double2 acc[4];
#pragma unroll
                for (int s = 0; s < 4; ++s) {
                    acc[s].x = (double)cur[s].x;
                    acc[s].y = (double)cur[s].y;
                }
                for (int kk = 0; kk < BS; ++kk) {
                    const double2 rv = *(const double2*)&Rsh[kk][j0];
#pragma unroll
                    for (int s = 0; s < 4; ++s) {
                        const double cc = Csh[rbase + rq + 8 * s][kk];
                        acc[s].x = fma(-cc, rv.x, acc[s].x);
                        acc[s].y = fma(-cc, rv.y, acc[s].y);
                    }
                }
#pragma unroll
                for (int s = 0; s < 4; ++s) {
                    float2 st;
                    st.x = (float)acc[s].x; st.y = (float)acc[s].y;
                    *(float2*)&A[(size_t)(rbase + rq + 8 * s) * N + j0] = st;
                }
            }
        }
        __syncthreads();
    }
}

// ---------------------------------------------------------------------------
// Kernel 4: epilogue. Minv = inv^T, so all reads are coalesced rows.
//  out[i][j] = (j!=0)*e*Minv[j][j] - (i!=0)*e*Minv[i][j] + (i==j)*e*Minv[0][i]
// ---------------------------------------------------------------------------
__global__ __launch_bounds__(1024) void finalize(const float* __restrict__ x,
                                                 const float* __restrict__ Minv,
                                                 float* __restrict__ out) {
    const int b = blockIdx.x;
    const int tid = threadIdx.x;
    const int j = tid & 255, iq = tid >> 8;
    const float* Iv = Minv + (size_t)b * N * N;
    const float* xb = x + (size_t)b * N * N;
    float* ob = out + (size_t)b * N * N;

    __shared__ float sdiag[N];
    __shared__ float sroot[N];
    if (iq == 0)      sdiag[j] = Iv[(size_t)j * N + j];
    else if (iq == 1) sroot[j] = Iv[j];                 // Minv row 0 = inv[:,0]
    __syncthreads();

    for (int i = iq; i < N; i += 4) {
        const float e  = expf(xb[(size_t)i * N + j]);
        const float t1 = (j == 0) ? 0.0f : e * sdiag[j];
        const float t2 = (i == 0) ? 0.0f : e * Iv[(size_t)i * N + j];
        float o = t1 - t2;
        if (i == j) o += e * sroot[i];
        ob[(size_t)i * N + j] = o;
    }
}

extern "C" void kernel_launch(void* const* d_in, const int* in_sizes, int n_in,
                              void* d_out, int out_size, void* d_ws, size_t ws_size,
                              hipStream_t stream) {
    const float* x = (const float*)d_in[0];
    float* out = (float*)d_out;

    size_t bytesA  = (size_t)B * N * N * sizeof(float);    // 64 MiB
    size_t bytesCS = (size_t)B * N * sizeof(double);       // 512 KiB
    if (ws_size < bytesA + bytesCS) return;

    float*  A  = (float*)d_ws;
    double* cs = (double*)((char*)d_ws + bytesA);

    colsum_k<<<B, 1024, 0, stream>>>(x, cs);
    build_t<<<dim3(64, B), 256, 0, stream>>>(x, cs, A);
    gj_blocked<<<B, 1024, 0, stream>>>(A);
    finalize<<<B, 1024, 0, stream>>>(x, A, out);
}

// Round 4
// 725.938 us; speedup vs baseline: 13.6086x; 3.5626x over previous
//
#include <hip/hip_runtime.h>
#include <math.h>

#define NB_ 8
#define N 256
#define BS 32
#define EPS 1e-5f

// One block per batch. 1024 threads; thread (ty,tx) = (tid>>5, tid&31) owns
// the 8x8 tile rows [8ty,8ty+8) x cols [8tx,8tx+8) of M = L^T in registers
// (fp32). All GJ arithmetic is fp64 on exactly-converted fp32 inputs; only
// inter-step storage rounds to fp32 (same error model as round 3: 2.4e-4).
__global__ __launch_bounds__(1024) void mtt_fused(const float* __restrict__ x,
                                                  float* __restrict__ out) {
    constexpr int LDR = N + 8;                       // 264 floats/row
    __shared__ alignas(16) float  Rf[BS][LDR];       // row panel / x strip (33.8KB)
    __shared__ float  Cf[N][BS + 1];                 // col panel (33.8KB)
    __shared__ double Ps[BS][BS + 1];                // pivot block fp64 (8.4KB)
    __shared__ double dsum[4][N];                    // colsum partials (8KB)
    __shared__ float  sdiag_f[N];
    __shared__ float  sroot_f[N];
    __shared__ double spiv_s;
    __shared__ int    spidx_s;
    __shared__ int    indx[BS];

    const int tid = threadIdx.x;
    const int ty = tid >> 5, tx = tid & 31;
    const int R0 = ty << 3, C0 = tx << 3;
    const float* xb = x + (size_t)blockIdx.x * N * N;
    float* ob = out + (size_t)blockIdx.x * N * N;

    float m[8][8];

    // ===================== PHASE 1: build M = L^T =====================
    double csacc = 0.0;                    // column partial (tq=tid>>8, jc=tid&255)
    const int tq = tid >> 8, jc = tid & 255;
    float exd[8];                          // exp(x[i][i]) for diag/col0 owners
#pragma unroll 1
    for (int s = 0; s < 8; ++s) {
        {   // coalesced strip load: x rows [32s,32s+32)
            const int rl = tid >> 5, c0 = (tid & 31) << 3;
            const float4 v0 = *(const float4*)&xb[(size_t)(32 * s + rl) * N + c0];
            const float4 v1 = *(const float4*)&xb[(size_t)(32 * s + rl) * N + c0 + 4];
            *(float4*)&Rf[rl][c0]     = v0;
            *(float4*)&Rf[rl][c0 + 4] = v1;
        }
        __syncthreads();
        // column sums (all rows; diag removed later)
#pragma unroll
        for (int r = 0; r < 8; ++r) csacc += (double)expf(Rf[(tq << 3) + r][jc]);
        // transpose-consume: threads whose cols fall in this strip
        if ((tx >> 2) == s) {
            const int jj0 = (tx << 3) - (s << 5);    // 0..24
#pragma unroll
            for (int c = 0; c < 8; ++c) {
#pragma unroll
                for (int r = 0; r < 8; ++r) {
                    const float e = expf(Rf[jj0 + c][R0 + r]);   // x[j][i]
                    m[r][c] = -(e + EPS);
                }
            }
        }
        // capture exp(x[i][i]) for diag-tile and col0-tile owners
        if ((ty >> 2) == s && (tx == ty || tx == 0)) {
            const int base = (ty << 3) - (s << 5);
#pragma unroll
            for (int r = 0; r < 8; ++r) exd[r] = expf(Rf[base + r][R0 + r]);
        }
        __syncthreads();
    }
    dsum[tq][jc] = csacc;
    __syncthreads();
    if (tid < N) {
        const double cst = dsum[0][tid] + dsum[1][tid] + dsum[2][tid] + dsum[3][tid];
        dsum[0][tid] = cst;   // same-thread RMW, safe
    }
    __syncthreads();
    if (tx == ty) {   // diag override: M[i][i] = colsum_i (i>0)
#pragma unroll
        for (int r = 0; r < 8; ++r) {
            const int i = R0 + r;
            if (i != 0)
                m[r][r] = (float)(dsum[0][i] - (double)exd[r] + 255.0 * (double)EPS);
        }
    }
    if (tx == 0) {    // col-0 override: M[i][0] = exp(x[i][i])
#pragma unroll
        for (int r = 0; r < 8; ++r) m[r][0] = exd[r];
    }
    __syncthreads();

    // ===================== PHASE 2: blocked GJ (8 steps) =====================
#pragma unroll 1
    for (int kb = 0; kb < NB_; ++kb) {
        const int q = kb << 2;
        const bool rowOwner = (ty >> 2) == kb;
        const bool colOwner = (tx >> 2) == kb;

        // (a) stage panels from registers
        if (rowOwner) {
            const int lr = (ty - q) << 3;
#pragma unroll
            for (int r = 0; r < 8; ++r)
#pragma unroll
                for (int c = 0; c < 8; ++c) Rf[lr + r][C0 + c] = m[r][c];
        }
        if (colOwner) {
            const int lc = (tx - q) << 3;
#pragma unroll
            for (int r = 0; r < 8; ++r)
#pragma unroll
                for (int c = 0; c < 8; ++c) Cf[R0 + r][lc + c] = m[r][c];
        }
        if (rowOwner && colOwner) {
            const int lr = (ty - q) << 3, lc = (tx - q) << 3;
#pragma unroll
            for (int r = 0; r < 8; ++r)
#pragma unroll
                for (int c = 0; c < 8; ++c) Ps[lr + r][lc + c] = (double)m[r][c];
        }
        __syncthreads();

        // (b) invert pivot block in LDS (fp64 GJ, partial pivoting)
        {
            const int r = ty, c = tx;
#pragma unroll 1
            for (int k2 = 0; k2 < BS; ++k2) {
                if (tid < 64) {
                    int rr = tid & 31;
                    double v  = Ps[rr][k2];
                    double av = (tid < 32 && rr >= k2) ? fabs(v) : -1.0;
                    int idx = rr;
                    for (int off = 16; off > 0; off >>= 1) {
                        double oav = __shfl_down(av, off);
                        double ov  = __shfl_down(v, off);
                        int    oi  = __shfl_down(idx, off);
                        if (oav > av) { av = oav; v = ov; idx = oi; }
                    }
                    if (tid == 0) { spidx_s = idx; spiv_s = 1.0 / v; indx[k2] = idx; }
                }
                __syncthreads();
                const int p = spidx_s;
                const double pivinv = spiv_s;
                const int sr = (r == k2) ? p : ((r == p) ? k2 : r);
                const double aval  = Ps[sr][c];
                const double prow  = Ps[p][c];
                const double scolr = Ps[sr][k2];
                __syncthreads();
                double nv;
                if (r == k2) {
                    nv = (c == k2) ? pivinv : prow * pivinv;
                } else {
                    const double srw  = (c == k2) ? pivinv : prow * pivinv;
                    const double base = (c == k2) ? 0.0 : aval;
                    nv = fma(-scolr, srw, base);
                }
                Ps[r][c] = nv;
                __syncthreads();
            }
            if (tid < 32) {
                for (int k2 = BS - 1; k2 >= 0; --k2) {
                    const int p = indx[k2];
                    if (p != k2) {
                        double t = Ps[tid][k2];
                        Ps[tid][k2] = Ps[tid][p];
                        Ps[tid][p]  = t;
                    }
                }
            }
            __syncthreads();
        }

        // (c) R' = P * Rold  (pivot cols get P itself); overwrite Rf
        {
            const int k  = ty;
            const int j0 = tx << 3;
            double acc[8];
            if ((tx >> 2) == kb) {
#pragma unroll
                for (int c = 0; c < 8; ++c) acc[c] = Ps[k][j0 + c - (kb << 5)];
            } else {
#pragma unroll
                for (int c = 0; c < 8; ++c) acc[c] = 0.0;
#pragma unroll 4
                for (int mm = 0; mm < BS; ++mm) {
                    const double pv = Ps[k][mm];
                    const float4 r0 = *(const float4*)&Rf[mm][j0];
                    const float4 r1 = *(const float4*)&Rf[mm][j0 + 4];
                    acc[0] = fma(pv, (double)r0.x, acc[0]);
                    acc[1] = fma(pv, (double)r0.y, acc[1]);
                    acc[2] = fma(pv, (double)r0.z, acc[2]);
                    acc[3] = fma(pv, (double)r0.w, acc[3]);
                    acc[4] = fma(pv, (double)r1.x, acc[4]);
                    acc[5] = fma(pv, (double)r1.y, acc[5]);
                    acc[6] = fma(pv, (double)r1.z, acc[6]);
                    acc[7] = fma(pv, (double)r1.w, acc[7]);
                }
            }
            __syncthreads();
#pragma unroll
            for (int c = 0; c < 8; ++c) Rf[k][j0 + c] = (float)acc[c];
        }
        __syncthreads();

        // (d) update own tile
        if (rowOwner) {
            const int lr = (ty - q) << 3;
#pragma unroll
            for (int r = 0; r < 8; ++r)
#pragma unroll
                for (int c = 0; c < 8; ++c) m[r][c] = Rf[lr + r][C0 + c];
        } else {
#pragma unroll
            for (int rp = 0; rp < 4; ++rp) {
                double a0[8], a1[8];
#pragma unroll
                for (int c = 0; c < 8; ++c) {
                    a0[c] = colOwner ? 0.0 : (double)m[2 * rp][c];
                    a1[c] = colOwner ? 0.0 : (double)m[2 * rp + 1][c];
                }
#pragma unroll 4
                for (int mm = 0; mm < BS; ++mm) {
                    const double c0 = -(double)Cf[R0 + 2 * rp][mm];
                    const double c1 = -(double)Cf[R0 + 2 * rp + 1][mm];
                    const float4 r0 = *(const float4*)&Rf[mm][C0];
                    const float4 r1 = *(const float4*)&Rf[mm][C0 + 4];
                    const double rv0 = (double)r0.x, rv1 = (double)r0.y;
                    const double rv2 = (double)r0.z, rv3 = (double)r0.w;
                    const double rv4 = (double)r1.x, rv5 = (double)r1.y;
                    const double rv6 = (double)r1.z, rv7 = (double)r1.w;
                    a0[0] = fma(c0, rv0, a0[0]); a1[0] = fma(c1, rv0, a1[0]);
                    a0[1] = fma(c0, rv1, a0[1]); a1[1] = fma(c1, rv1, a1[1]);
                    a0[2] = fma(c0, rv2, a0[2]); a1[2] = fma(c1, rv2, a1[2]);
                    a0[3] = fma(c0, rv3, a0[3]); a1[3] = fma(c1, rv3, a1[3]);
                    a0[4] = fma(c0, rv4, a0[4]); a1[4] = fma(c1, rv4, a1[4]);
                    a0[5] = fma(c0, rv5, a0[5]); a1[5] = fma(c1, rv5, a1[5]);
                    a0[6] = fma(c0, rv6, a0[6]); a1[6] = fma(c1, rv6, a1[6]);
                    a0[7] = fma(c0, rv7, a0[7]); a1[7] = fma(c1, rv7, a1[7]);
                }
#pragma unroll
                for (int c = 0; c < 8; ++c) {
                    m[2 * rp][c]     = (float)a0[c];
                    m[2 * rp + 1][c] = (float)a1[c];
                }
            }
        }
        __syncthreads();
    }

    // ===================== PHASE 3: epilogue =====================
    if (tx == ty) {
#pragma unroll
        for (int r = 0; r < 8; ++r) sdiag_f[R0 + r] = m[r][r];
    }
    if (ty == 0) {
#pragma unroll
        for (int c = 0; c < 8; ++c) sroot_f[C0 + c] = m[0][c];
    }
    __syncthreads();

    float sd[8];
    {
        const float4 s0 = *(const float4*)&sdiag_f[C0];
        const float4 s1 = *(const float4*)&sdiag_f[C0 + 4];
        sd[0] = s0.x; sd[1] = s0.y; sd[2] = s0.z; sd[3] = s0.w;
        sd[4] = s1.x; sd[5] = s1.y; sd[6] = s1.z; sd[7] = s1.w;
    }
#pragma unroll
    for (int r = 0; r < 8; ++r) {
        const int a = R0 + r;
        const float4 x0 = *(const float4*)&xb[(size_t)a * N + C0];
        const float4 x1 = *(const float4*)&xb[(size_t)a * N + C0 + 4];
        const float xv[8] = {x0.x, x0.y, x0.z, x0.w, x1.x, x1.y, x1.z, x1.w};
        const float rt = sroot_f[a];       // wave-broadcast read
        float ov[8];
#pragma unroll
        for (int c = 0; c < 8; ++c) {
            const int b_ = C0 + c;
            const float e = expf(xv[c]);
            float o = (b_ == 0) ? 0.0f : e * sd[c];
            if (a != 0) o -= e * m[r][c];          // e * inv^T[a][b]
            if (a == b_) o += e * rt;              // e * inv[a][0]
            ov[c] = o;
        }
        *(float4*)&ob[(size_t)a * N + C0]     = make_float4(ov[0], ov[1], ov[2], ov[3]);
        *(float4*)&ob[(size_t)a * N + C0 + 4] = make_float4(ov[4], ov[5], ov[6], ov[7]);
    }
}

extern "C" void kernel_launch(void* const* d_in, const int* in_sizes, int n_in,
                              void* d_out, int out_size, void* d_ws, size_t ws_size,
                              hipStream_t stream) {
    const float* x = (const float*)d_in[0];
    float* out = (float*)d_out;
    mtt_fused<<<256, 1024, 0, stream>>>(x, out);
}

// Round 5
// 508.593 us; speedup vs baseline: 19.4242x; 1.4273x over previous
//
#include <hip/hip_runtime.h>
#include <math.h>

#define N 256
#define BS 32
#define NB_ 8
#define EPS 1e-5f

// One block per batch, 1024 threads. Thread (ty,tx)=(tid>>5,tid&31) owns an
// 8x8 tile of M = L^T: rows [8ty,8ty+8), cols {tx*4..tx*4+3} u {128+tx*4..+3}
// (split-column mapping -> all panel LDS reads are contiguous 512B spans,
// conflict-free). Pivot-block inversion + colsums + R'=P*R in fp64; trailing
// rank-32 updates in fp32 (in-place into m, Rf read once per k).
__global__ __launch_bounds__(1024) void mtt_fused(const float* __restrict__ x,
                                                  float* __restrict__ out) {
    constexpr int LDR = N + 8;
    __shared__ alignas(16) float  Rf[BS][LDR];     // row panel (R', fp32) 33.8KB
    __shared__ alignas(16) float  CfT[BS][LDR];    // col panel TRANSPOSED  33.8KB
    __shared__ double Ps[BS][BS + 1];              // pivot block fp64      8.4KB
    __shared__ double dsum[4][N];                  // colsum partials       8KB
    __shared__ float  sdiag_f[N];
    __shared__ float  sroot_f[N];
    __shared__ double spiv_s;
    __shared__ int    spidx_s;
    __shared__ int    indx[BS];

    const int tid = threadIdx.x;
    const int ty = tid >> 5, tx = tid & 31;
    const int R0  = ty << 3;
    const int c0a = tx << 2;            // first-half col base  (cols 0..127)
    const int c0b = 128 + (tx << 2);    // second-half col base (cols 128..255)
    const int hibase = (ty >= 16) ? 4 : 0;
    const float* xb = x + (size_t)blockIdx.x * N * N;
    float* ob = out + (size_t)blockIdx.x * N * N;

    float m[8][8];

    // ===================== PHASE 1: build M = L^T =====================
    double csacc = 0.0;
    const int tq = tid >> 8, jc = tid & 255;
    float exd[8];
    const bool needExd =
        (tx == 0) || (tx == ((2 * ty) & 31)) || (tx == ((2 * ty + 1) & 31));

#pragma unroll 1
    for (int s = 0; s < 8; ++s) {
        {   // coalesced strip load: x rows [32s,32s+32) -> Rf
            const int cc0 = tx << 3;
            const float4 v0 = *(const float4*)&xb[(size_t)(32 * s + ty) * N + cc0];
            const float4 v1 = *(const float4*)&xb[(size_t)(32 * s + ty) * N + cc0 + 4];
            *(float4*)&Rf[ty][cc0]     = v0;
            *(float4*)&Rf[ty][cc0 + 4] = v1;
        }
        __syncthreads();
#pragma unroll
        for (int r = 0; r < 8; ++r) csacc += (double)expf(Rf[(tq << 3) + r][jc]);
        // transpose-consume: first-half cols in strip s, second-half in s-4
        if ((tx >> 3) == s) {
            const int jb = (tx & 7) << 2;
#pragma unroll
            for (int cc = 0; cc < 4; ++cc)
#pragma unroll
                for (int r = 0; r < 8; ++r)
                    m[r][cc] = -(expf(Rf[jb + cc][R0 + r]) + EPS);
        }
        if (s >= 4 && (tx >> 3) == s - 4) {
            const int jb = (tx & 7) << 2;
#pragma unroll
            for (int cc = 0; cc < 4; ++cc)
#pragma unroll
                for (int r = 0; r < 8; ++r)
                    m[r][4 + cc] = -(expf(Rf[jb + cc][R0 + r]) + EPS);
        }
        if (needExd && (ty >> 2) == s) {
            const int base = R0 - (s << 5);
#pragma unroll
            for (int r = 0; r < 8; ++r) exd[r] = expf(Rf[base + r][R0 + r]);
        }
        __syncthreads();
    }
    dsum[tq][jc] = csacc;
    __syncthreads();
    if (tid < N)
        dsum[0][tid] = dsum[0][tid] + dsum[1][tid] + dsum[2][tid] + dsum[3][tid];
    __syncthreads();
    // diag override: M[i][i] = colsum_i (i>0); diag of row r lives at
    // tx = (2ty + (r>=4)) & 31, col index (r&3)+hibase
#pragma unroll
    for (int r = 0; r < 8; ++r) {
        const int hb = r >> 2;
        if (tx == ((2 * ty + hb) & 31)) {
            const int i = R0 + r;
            if (i != 0)
                m[r][(r & 3) + hibase] =
                    (float)(dsum[0][i] - (double)exd[r] + 255.0 * (double)EPS);
        }
    }
    if (tx == 0) {   // col-0 override: M[i][0] = exp(x[i][i])
#pragma unroll
        for (int r = 0; r < 8; ++r) m[r][0] = exd[r];
    }

    // ===================== PHASE 2: blocked GJ (8 steps) =====================
#pragma unroll 1
    for (int kb = 0; kb < NB_; ++kb) {
        const bool rowOwner = (ty >> 2) == kb;
        const bool h0piv = (kb < 4) && ((tx >> 3) == kb);
        const bool h1piv = (kb >= 4) && ((tx >> 3) == kb - 4);
        const int lr = (ty - (kb << 2)) << 3;   // valid when rowOwner
        const int lc = (tx & 7) << 2;           // valid when h0piv/h1piv

        // ---- (a) stage panels from registers ----
        if (rowOwner) {
#pragma unroll
            for (int r = 0; r < 8; ++r) {
                *(float4*)&Rf[lr + r][c0a] =
                    make_float4(m[r][0], m[r][1], m[r][2], m[r][3]);
                *(float4*)&Rf[lr + r][c0b] =
                    make_float4(m[r][4], m[r][5], m[r][6], m[r][7]);
            }
        }
        if (h0piv || h1piv) {
            const int cb = h0piv ? 0 : 4;
#pragma unroll
            for (int cc = 0; cc < 4; ++cc) {
                *(float4*)&CfT[lc + cc][R0] =
                    make_float4(m[0][cb + cc], m[1][cb + cc], m[2][cb + cc], m[3][cb + cc]);
                *(float4*)&CfT[lc + cc][R0 + 4] =
                    make_float4(m[4][cb + cc], m[5][cb + cc], m[6][cb + cc], m[7][cb + cc]);
            }
        }
        if (rowOwner && (h0piv || h1piv)) {
            const int cb = h0piv ? 0 : 4;
#pragma unroll
            for (int r = 0; r < 8; ++r)
#pragma unroll
                for (int cc = 0; cc < 4; ++cc)
                    Ps[lr + r][lc + cc] = (double)m[r][cb + cc];
        }
        __syncthreads();

        // ---- (b) invert pivot block in LDS (fp64 GJ, partial pivoting) ----
        {
            const int r = ty, c = tx;
#pragma unroll 1
            for (int k2 = 0; k2 < BS; ++k2) {
                if (tid < 64) {
                    int rr = tid & 31;
                    double v  = Ps[rr][k2];
                    double av = (tid < 32 && rr >= k2) ? fabs(v) : -1.0;
                    int idx = rr;
                    for (int off = 16; off > 0; off >>= 1) {
                        double oav = __shfl_down(av, off);
                        double ov  = __shfl_down(v, off);
                        int    oi  = __shfl_down(idx, off);
                        if (oav > av) { av = oav; v = ov; idx = oi; }
                    }
                    if (tid == 0) { spidx_s = idx; spiv_s = 1.0 / v; indx[k2] = idx; }
                }
                __syncthreads();
                const int p = spidx_s;
                const double pivinv = spiv_s;
                const int sr = (r == k2) ? p : ((r == p) ? k2 : r);
                const double aval  = Ps[sr][c];
                const double prow  = Ps[p][c];
                const double scolr = Ps[sr][k2];
                __syncthreads();
                double nv;
                if (r == k2) {
                    nv = (c == k2) ? pivinv : prow * pivinv;
                } else {
                    const double srw  = (c == k2) ? pivinv : prow * pivinv;
                    const double base = (c == k2) ? 0.0 : aval;
                    nv = fma(-scolr, srw, base);
                }
                Ps[r][c] = nv;
                __syncthreads();
            }
            if (tid < 32) {
                for (int k2 = BS - 1; k2 >= 0; --k2) {
                    const int p = indx[k2];
                    if (p != k2) {
                        double t = Ps[tid][k2];
                        Ps[tid][k2] = Ps[tid][p];
                        Ps[tid][p]  = t;
                    }
                }
            }
            __syncthreads();
        }

        // ---- (c) R' = P * Rold (fp64 acc); pivot cols <- P; Rf <- R' ----
        {
            double acc[8];
#pragma unroll
            for (int c = 0; c < 8; ++c) acc[c] = 0.0;
#pragma unroll 4
            for (int mm = 0; mm < BS; ++mm) {
                const double pv = Ps[ty][mm];
                const float4 r0 = *(const float4*)&Rf[mm][c0a];
                const float4 r1 = *(const float4*)&Rf[mm][c0b];
                acc[0] = fma(pv, (double)r0.x, acc[0]);
                acc[1] = fma(pv, (double)r0.y, acc[1]);
                acc[2] = fma(pv, (double)r0.z, acc[2]);
                acc[3] = fma(pv, (double)r0.w, acc[3]);
                acc[4] = fma(pv, (double)r1.x, acc[4]);
                acc[5] = fma(pv, (double)r1.y, acc[5]);
                acc[6] = fma(pv, (double)r1.z, acc[6]);
                acc[7] = fma(pv, (double)r1.w, acc[7]);
            }
            if (h0piv) {
#pragma unroll
                for (int cc = 0; cc < 4; ++cc) acc[cc] = Ps[ty][lc + cc];
            }
            if (h1piv) {
#pragma unroll
                for (int cc = 0; cc < 4; ++cc) acc[4 + cc] = Ps[ty][lc + cc];
            }
            __syncthreads();
            *(float4*)&Rf[ty][c0a] =
                make_float4((float)acc[0], (float)acc[1], (float)acc[2], (float)acc[3]);
            *(float4*)&Rf[ty][c0b] =
                make_float4((float)acc[4], (float)acc[5], (float)acc[6], (float)acc[7]);
        }
        __syncthreads();

        // ---- (d) tile update ----
        if (rowOwner) {
            // pivot-row-block tiles take R' rows directly
#pragma unroll
            for (int r = 0; r < 8; ++r) {
                const float4 a0 = *(const float4*)&Rf[lr + r][c0a];
                const float4 a1 = *(const float4*)&Rf[lr + r][c0b];
                m[r][0] = a0.x; m[r][1] = a0.y; m[r][2] = a0.z; m[r][3] = a0.w;
                m[r][4] = a1.x; m[r][5] = a1.y; m[r][6] = a1.z; m[r][7] = a1.w;
            }
        } else {
            // pivot-col halves restart from 0 (C' = -C*P comes out of the GEMM)
            if (h0piv) {
#pragma unroll
                for (int r = 0; r < 8; ++r) { m[r][0] = 0.f; m[r][1] = 0.f; m[r][2] = 0.f; m[r][3] = 0.f; }
            }
            if (h1piv) {
#pragma unroll
                for (int r = 0; r < 8; ++r) { m[r][4] = 0.f; m[r][5] = 0.f; m[r][6] = 0.f; m[r][7] = 0.f; }
            }
#pragma unroll 2
            for (int mm = 0; mm < BS; ++mm) {
                const float4 rv0 = *(const float4*)&Rf[mm][c0a];
                const float4 rv1 = *(const float4*)&Rf[mm][c0b];
                const float4 cv0 = *(const float4*)&CfT[mm][R0];
                const float4 cv1 = *(const float4*)&CfT[mm][R0 + 4];
                const float cr[8] = {-cv0.x, -cv0.y, -cv0.z, -cv0.w,
                                     -cv1.x, -cv1.y, -cv1.z, -cv1.w};
#pragma unroll
                for (int r = 0; r < 8; ++r) {
                    m[r][0] = fmaf(cr[r], rv0.x, m[r][0]);
                    m[r][1] = fmaf(cr[r], rv0.y, m[r][1]);
                    m[r][2] = fmaf(cr[r], rv0.z, m[r][2]);
                    m[r][3] = fmaf(cr[r], rv0.w, m[r][3]);
                    m[r][4] = fmaf(cr[r], rv1.x, m[r][4]);
                    m[r][5] = fmaf(cr[r], rv1.y, m[r][5]);
                    m[r][6] = fmaf(cr[r], rv1.z, m[r][6]);
                    m[r][7] = fmaf(cr[r], rv1.w, m[r][7]);
                }
            }
        }
        __syncthreads();
    }

    // ===================== PHASE 3: epilogue =====================
#pragma unroll
    for (int r = 0; r < 8; ++r) {
        const int hb = r >> 2;
        if (tx == ((2 * ty + hb) & 31))
            sdiag_f[R0 + r] = m[r][(r & 3) + hibase];
    }
    if (ty == 0) {
        *(float4*)&sroot_f[c0a] = make_float4(m[0][0], m[0][1], m[0][2], m[0][3]);
        *(float4*)&sroot_f[c0b] = make_float4(m[0][4], m[0][5], m[0][6], m[0][7]);
    }
    __syncthreads();

    float sd[8];
    {
        const float4 s0 = *(const float4*)&sdiag_f[c0a];
        const float4 s1 = *(const float4*)&sdiag_f[c0b];
        sd[0] = s0.x; sd[1] = s0.y; sd[2] = s0.z; sd[3] = s0.w;
        sd[4] = s1.x; sd[5] = s1.y; sd[6] = s1.z; sd[7] = s1.w;
    }
#pragma unroll
    for (int r = 0; r < 8; ++r) {
        const int a = R0 + r;
        const float4 x0 = *(const float4*)&xb[(size_t)a * N + c0a];
        const float4 x1 = *(const float4*)&xb[(size_t)a * N + c0b];
        const float xv[8] = {x0.x, x0.y, x0.z, x0.w, x1.x, x1.y, x1.z, x1.w};
        const float rt = sroot_f[a];
        float ov[8];
#pragma unroll
        for (int c = 0; c < 8; ++c) {
            const int b_ = (c < 4) ? (c0a + c) : (c0b + (c - 4));
            const float e = expf(xv[c]);
            float o = (b_ == 0) ? 0.0f : e * sd[c];
            if (a != 0) o -= e * m[r][c];          // e * inv^T[a][b]
            if (a == b_) o += e * rt;              // e * inv[a][0]
            ov[c] = o;
        }
        *(float4*)&ob[(size_t)a * N + c0a] = make_float4(ov[0], ov[1], ov[2], ov[3]);
        *(float4*)&ob[(size_t)a * N + c0b] = make_float4(ov[4], ov[5], ov[6], ov[7]);
    }
}

extern "C" void kernel_launch(void* const* d_in, const int* in_sizes, int n_in,
                              void* d_out, int out_size, void* d_ws, size_t ws_size,
                              hipStream_t stream) {
    const float* x = (const float*)d_in[0];
    float* out = (float*)d_out;
    mtt_fused<<<256, 1024, 0, stream>>>(x, out);
}

// Round 6
// 438.254 us; speedup vs baseline: 22.5417x; 1.1605x over previous
//
#include <hip/hip_runtime.h>
#include <math.h>

#define N 256
#define BS 32
#define NB_ 8
#define EPS 1e-5f

// One block per batch, 512 threads. Thread (ty,tx)=(tid>>5,tid&31) owns a
// 16x8 tile of M = L^T: rows [16ty,16ty+16), cols {4tx..4tx+3} u {128+4tx..+3}.
// m[16][8] = 128 VGPRs; __launch_bounds__(512,2) -> 256-reg cap -> no spill.
// fp64: pivot-block inversion + colsums. fp32: panels, R'=P*R, trailing GEMM.
__global__ __launch_bounds__(512, 2) void mtt_fused(const float* __restrict__ x,
                                                    float* __restrict__ out) {
    constexpr int LDR = N + 8;
    __shared__ alignas(16) float  Rf[BS][LDR];     // row panel / x strip  33.8KB
    __shared__ alignas(16) float  CfT[BS][LDR];    // col panel, transposed 33.8KB
    __shared__ double Ps[BS][BS + 1];              // pivot block fp64      8.4KB
    __shared__ float  Pf[BS][BS + 1];              // pivot block fp32      4.2KB
    __shared__ double dsum[2][N];                  // colsum partials       4KB
    __shared__ float  sdx[N];                      // exp(x[i][i])          1KB
    __shared__ float  sdiag_f[N];
    __shared__ float  sroot_f[N];
    __shared__ int    indx[BS];

    const int tid = threadIdx.x;
    const int ty = tid >> 5, tx = tid & 31;
    const int R0  = ty << 4;
    const int c0a = tx << 2;
    const int c0b = 128 + (tx << 2);
    const float* xb = x + (size_t)blockIdx.x * N * N;
    float* ob = out + (size_t)blockIdx.x * N * N;

    float m[16][8];

    // ===================== PHASE 1: build M = L^T =====================
    double csacc = 0.0;
    const int tq = tid >> 8, jc = tid & 255;
#pragma unroll 1
    for (int s = 0; s < 8; ++s) {
        {   // coalesced strip load: x rows [32s,32s+32) -> Rf
            const int rl = tid >> 4, cl = (tid & 15) << 4;
            const float* src = &xb[(size_t)(32 * s + rl) * N + cl];
            *(float4*)&Rf[rl][cl]      = *(const float4*)&src[0];
            *(float4*)&Rf[rl][cl + 4]  = *(const float4*)&src[4];
            *(float4*)&Rf[rl][cl + 8]  = *(const float4*)&src[8];
            *(float4*)&Rf[rl][cl + 12] = *(const float4*)&src[12];
        }
        __syncthreads();
#pragma unroll
        for (int r = 0; r < 16; ++r)
            csacc += (double)expf(Rf[(tq << 4) + r][jc]);
        if (tid < 32) sdx[32 * s + tid] = expf(Rf[tid][32 * s + tid]);
        if ((tx >> 3) == s) {              // first-half cols live in strips 0-3
            const int jb = (tx & 7) << 2;
#pragma unroll
            for (int cc = 0; cc < 4; ++cc)
#pragma unroll
                for (int r = 0; r < 16; ++r)
                    m[r][cc] = -(expf(Rf[jb + cc][R0 + r]) + EPS);
        }
        if (s >= 4 && (tx >> 3) == s - 4) { // second-half cols: strips 4-7
            const int jb = (tx & 7) << 2;
#pragma unroll
            for (int cc = 0; cc < 4; ++cc)
#pragma unroll
                for (int r = 0; r < 16; ++r)
                    m[r][4 + cc] = -(expf(Rf[jb + cc][R0 + r]) + EPS);
        }
        __syncthreads();
    }
    dsum[tq][jc] = csacc;
    __syncthreads();
    if (tid < N) dsum[0][tid] += dsum[1][tid];
    __syncthreads();
    // diag override: M[i][i] = colsum_i (i>0)   [static m-indices per half]
    if (ty < 8) {
#pragma unroll
        for (int r = 0; r < 16; ++r) {
            const int i = R0 + r;
            if (tx == (i >> 2) && i != 0)
                m[r][r & 3] =
                    (float)(dsum[0][i] - (double)sdx[i] + 255.0 * (double)EPS);
        }
    } else {
#pragma unroll
        for (int r = 0; r < 16; ++r) {
            const int i = R0 + r;
            if (tx == ((i - 128) >> 2))
                m[r][4 + (r & 3)] =
                    (float)(dsum[0][i] - (double)sdx[i] + 255.0 * (double)EPS);
        }
    }
    if (tx == 0) {   // col-0 override: M[i][0] = exp(x[i][i])
#pragma unroll
        for (int r = 0; r < 16; ++r) m[r][0] = sdx[R0 + r];
    }

    // ===================== PHASE 2: blocked GJ (8 steps) =====================
#pragma unroll 1
    for (int kb = 0; kb < NB_; ++kb) {
        const bool rowOwner = (ty >> 1) == kb;
        const bool h0piv = (kb < 4) && ((tx >> 3) == kb);
        const bool h1piv = (kb >= 4) && ((tx >> 3) == kb - 4);
        const int lr = (ty - (kb << 1)) << 4;   // 0 or 16 when rowOwner
        const int lc = (tx & 7) << 2;

        // ---- (a) stage panels from registers ----
        if (rowOwner) {
#pragma unroll
            for (int r = 0; r < 16; ++r) {
                *(float4*)&Rf[lr + r][c0a] =
                    make_float4(m[r][0], m[r][1], m[r][2], m[r][3]);
                *(float4*)&Rf[lr + r][c0b] =
                    make_float4(m[r][4], m[r][5], m[r][6], m[r][7]);
            }
        }
        if (h0piv) {
#pragma unroll
            for (int cc = 0; cc < 4; ++cc) {
                *(float4*)&CfT[lc + cc][R0]      = make_float4(m[0][cc],  m[1][cc],  m[2][cc],  m[3][cc]);
                *(float4*)&CfT[lc + cc][R0 + 4]  = make_float4(m[4][cc],  m[5][cc],  m[6][cc],  m[7][cc]);
                *(float4*)&CfT[lc + cc][R0 + 8]  = make_float4(m[8][cc],  m[9][cc],  m[10][cc], m[11][cc]);
                *(float4*)&CfT[lc + cc][R0 + 12] = make_float4(m[12][cc], m[13][cc], m[14][cc], m[15][cc]);
            }
            if (rowOwner) {
#pragma unroll
                for (int r = 0; r < 16; ++r)
#pragma unroll
                    for (int cc = 0; cc < 4; ++cc)
                        Ps[lr + r][lc + cc] = (double)m[r][cc];
            }
        }
        if (h1piv) {
#pragma unroll
            for (int cc = 0; cc < 4; ++cc) {
                *(float4*)&CfT[lc + cc][R0]      = make_float4(m[0][4+cc],  m[1][4+cc],  m[2][4+cc],  m[3][4+cc]);
                *(float4*)&CfT[lc + cc][R0 + 4]  = make_float4(m[4][4+cc],  m[5][4+cc],  m[6][4+cc],  m[7][4+cc]);
                *(float4*)&CfT[lc + cc][R0 + 8]  = make_float4(m[8][4+cc],  m[9][4+cc],  m[10][4+cc], m[11][4+cc]);
                *(float4*)&CfT[lc + cc][R0 + 12] = make_float4(m[12][4+cc], m[13][4+cc], m[14][4+cc], m[15][4+cc]);
            }
            if (rowOwner) {
#pragma unroll
                for (int r = 0; r < 16; ++r)
#pragma unroll
                    for (int cc = 0; cc < 4; ++cc)
                        Ps[lr + r][lc + cc] = (double)m[r][4 + cc];
            }
        }
        __syncthreads();

        // ---- (b) invert pivot block (fp64, partial pivot, butterfly search) ----
        {
            const int rr = tid & 31;          // search row for this lane
            const int r0 = ty, r1 = ty + 16, c = tx;
#pragma unroll 1
            for (int k2 = 0; k2 < BS; ++k2) {
                double v  = Ps[rr][k2];
                double av = (rr >= k2) ? fabs(v) : -1.0;
                int idx = rr;
#pragma unroll
                for (int off = 1; off < 64; off <<= 1) {
                    const double oav = __shfl_xor(av, off);
                    const double ov  = __shfl_xor(v, off);
                    const int    oi  = __shfl_xor(idx, off);
                    if (oav > av || (oav == av && oi < idx)) { av = oav; v = ov; idx = oi; }
                }
                const int p = idx;
                const double pivinv = 1.0 / v;
                if (tid == 0) indx[k2] = p;
                const int sr0 = (r0 == k2) ? p : ((r0 == p) ? k2 : r0);
                const int sr1 = (r1 == k2) ? p : ((r1 == p) ? k2 : r1);
                const double prow  = Ps[p][c];
                const double aval0 = Ps[sr0][c], scol0 = Ps[sr0][k2];
                const double aval1 = Ps[sr1][c], scol1 = Ps[sr1][k2];
                __syncthreads();
                const double srw = (c == k2) ? pivinv : prow * pivinv;
                const double b0  = (c == k2) ? 0.0 : aval0;
                const double b1  = (c == k2) ? 0.0 : aval1;
                Ps[r0][c] = (r0 == k2) ? srw : fma(-scol0, srw, b0);
                Ps[r1][c] = (r1 == k2) ? srw : fma(-scol1, srw, b1);
                __syncthreads();
            }
            if (tid < 32) {   // column unscramble, thread tid owns row tid
                for (int k2 = BS - 1; k2 >= 0; --k2) {
                    const int p = indx[k2];
                    if (p != k2) {
                        double t = Ps[tid][k2];
                        Ps[tid][k2] = Ps[tid][p];
                        Ps[tid][p]  = t;
                    }
                }
            }
            __syncthreads();
            Pf[ty][tx]      = (float)Ps[ty][tx];
            Pf[ty + 16][tx] = (float)Ps[ty + 16][tx];
            __syncthreads();
        }

        // ---- (c) R' = P * Rold (fp32); pivot cols <- P; Rf <- R' ----
        {
            float a0[8], a1[8];
#pragma unroll
            for (int c = 0; c < 8; ++c) { a0[c] = 0.f; a1[c] = 0.f; }
#pragma unroll 2
            for (int mm = 0; mm < BS; ++mm) {
                const float p0 = Pf[ty][mm];
                const float p1 = Pf[ty + 16][mm];
                const float4 r0 = *(const float4*)&Rf[mm][c0a];
                const float4 r1 = *(const float4*)&Rf[mm][c0b];
                a0[0] = fmaf(p0, r0.x, a0[0]);  a1[0] = fmaf(p1, r0.x, a1[0]);
                a0[1] = fmaf(p0, r0.y, a0[1]);  a1[1] = fmaf(p1, r0.y, a1[1]);
                a0[2] = fmaf(p0, r0.z, a0[2]);  a1[2] = fmaf(p1, r0.z, a1[2]);
                a0[3] = fmaf(p0, r0.w, a0[3]);  a1[3] = fmaf(p1, r0.w, a1[3]);
                a0[4] = fmaf(p0, r1.x, a0[4]);  a1[4] = fmaf(p1, r1.x, a1[4]);
                a0[5] = fmaf(p0, r1.y, a0[5]);  a1[5] = fmaf(p1, r1.y, a1[5]);
                a0[6] = fmaf(p0, r1.z, a0[6]);  a1[6] = fmaf(p1, r1.z, a1[6]);
                a0[7] = fmaf(p0, r1.w, a0[7]);  a1[7] = fmaf(p1, r1.w, a1[7]);
            }
            if (h0piv) {
#pragma unroll
                for (int cc = 0; cc < 4; ++cc) {
                    a0[cc] = Pf[ty][lc + cc];
                    a1[cc] = Pf[ty + 16][lc + cc];
                }
            }
            if (h1piv) {
#pragma unroll
                for (int cc = 0; cc < 4; ++cc) {
                    a0[4 + cc] = Pf[ty][lc + cc];
                    a1[4 + cc] = Pf[ty + 16][lc + cc];
                }
            }
            __syncthreads();
            *(float4*)&Rf[ty][c0a]      = make_float4(a0[0], a0[1], a0[2], a0[3]);
            *(float4*)&Rf[ty][c0b]      = make_float4(a0[4], a0[5], a0[6], a0[7]);
            *(float4*)&Rf[ty + 16][c0a] = make_float4(a1[0], a1[1], a1[2], a1[3]);
            *(float4*)&Rf[ty + 16][c0b] = make_float4(a1[4], a1[5], a1[6], a1[7]);
        }
        __syncthreads();

        // ---- (d) tile update ----
        if (rowOwner) {
#pragma unroll
            for (int r = 0; r < 16; ++r) {
                const float4 b0 = *(const float4*)&Rf[lr + r][c0a];
                const float4 b1 = *(const float4*)&Rf[lr + r][c0b];
                m[r][0] = b0.x; m[r][1] = b0.y; m[r][2] = b0.z; m[r][3] = b0.w;
                m[r][4] = b1.x; m[r][5] = b1.y; m[r][6] = b1.z; m[r][7] = b1.w;
            }
        } else {
            if (h0piv) {
#pragma unroll
                for (int r = 0; r < 16; ++r) {
                    m[r][0] = 0.f; m[r][1] = 0.f; m[r][2] = 0.f; m[r][3] = 0.f;
                }
            }
            if (h1piv) {
#pragma unroll
                for (int r = 0; r < 16; ++r) {
                    m[r][4] = 0.f; m[r][5] = 0.f; m[r][6] = 0.f; m[r][7] = 0.f;
                }
            }
#pragma unroll 2
            for (int mm = 0; mm < BS; ++mm) {
                const float4 rv0 = *(const float4*)&Rf[mm][c0a];
                const float4 rv1 = *(const float4*)&Rf[mm][c0b];
                const float4 cv0 = *(const float4*)&CfT[mm][R0];
                const float4 cv1 = *(const float4*)&CfT[mm][R0 + 4];
                const float4 cv2 = *(const float4*)&CfT[mm][R0 + 8];
                const float4 cv3 = *(const float4*)&CfT[mm][R0 + 12];
                const float cc16[16] = {cv0.x, cv0.y, cv0.z, cv0.w,
                                        cv1.x, cv1.y, cv1.z, cv1.w,
                                        cv2.x, cv2.y, cv2.z, cv2.w,
                                        cv3.x, cv3.y, cv3.z, cv3.w};
#pragma unroll
                for (int r = 0; r < 16; ++r) {
                    const float cr = -cc16[r];
                    m[r][0] = fmaf(cr, rv0.x, m[r][0]);
                    m[r][1] = fmaf(cr, rv0.y, m[r][1]);
                    m[r][2] = fmaf(cr, rv0.z, m[r][2]);
                    m[r][3] = fmaf(cr, rv0.w, m[r][3]);
                    m[r][4] = fmaf(cr, rv1.x, m[r][4]);
                    m[r][5] = fmaf(cr, rv1.y, m[r][5]);
                    m[r][6] = fmaf(cr, rv1.z, m[r][6]);
                    m[r][7] = fmaf(cr, rv1.w, m[r][7]);
                }
            }
        }
        __syncthreads();
    }

    // ===================== PHASE 3: epilogue =====================
    if (ty < 8) {
#pragma unroll
        for (int r = 0; r < 16; ++r) {
            const int i = R0 + r;
            if (tx == (i >> 2)) sdiag_f[i] = m[r][r & 3];
        }
    } else {
#pragma unroll
        for (int r = 0; r < 16; ++r) {
            const int i = R0 + r;
            if (tx == ((i - 128) >> 2)) sdiag_f[i] = m[r][4 + (r & 3)];
        }
    }
    if (ty == 0) {
        *(float4*)&sroot_f[c0a] = make_float4(m[0][0], m[0][1], m[0][2], m[0][3]);
        *(float4*)&sroot_f[c0b] = make_float4(m[0][4], m[0][5], m[0][6], m[0][7]);
    }
    __syncthreads();

    float sd[8];
    {
        const float4 s0 = *(const float4*)&sdiag_f[c0a];
        const float4 s1 = *(const float4*)&sdiag_f[c0b];
        sd[0] = s0.x; sd[1] = s0.y; sd[2] = s0.z; sd[3] = s0.w;
        sd[4] = s1.x; sd[5] = s1.y; sd[6] = s1.z; sd[7] = s1.w;
    }
#pragma unroll
    for (int r = 0; r < 16; ++r) {
        const int a = R0 + r;
        const float4 x0 = *(const float4*)&xb[(size_t)a * N + c0a];
        const float4 x1 = *(const float4*)&xb[(size_t)a * N + c0b];
        const float xv[8] = {x0.x, x0.y, x0.z, x0.w, x1.x, x1.y, x1.z, x1.w};
        const float rt = sroot_f[a];
        float ov[8];
#pragma unroll
        for (int c = 0; c < 8; ++c) {
            const int b_ = (c < 4) ? (c0a + c) : (c0b + (c - 4));
            const float e = expf(xv[c]);
            float o = (b_ == 0) ? 0.0f : e * sd[c];
            if (a != 0) o -= e * m[r][c];          // e * inv^T[a][b]
            if (a == b_) o += e * rt;              // e * inv[a][0]
            ov[c] = o;
        }
        *(float4*)&ob[(size_t)a * N + c0a] = make_float4(ov[0], ov[1], ov[2], ov[3]);
        *(float4*)&ob[(size_t)a * N + c0b] = make_float4(ov[4], ov[5], ov[6], ov[7]);
    }
}

extern "C" void kernel_launch(void* const* d_in, const int* in_sizes, int n_in,
                              void* d_out, int out_size, void* d_ws, size_t ws_size,
                              hipStream_t stream) {
    const float* x = (const float*)d_in[0];
    float* out = (float*)d_out;
    mtt_fused<<<256, 512, 0, stream>>>(x, out);
}